// Round 2
// baseline (1613.881 us; speedup 1.0000x reference)
//
#include <hip/hip_runtime.h>
#include <math.h>

typedef __attribute__((ext_vector_type(8))) short short8;    // 8 x bf16
typedef __attribute__((ext_vector_type(4))) float f32x4;
typedef __attribute__((ext_vector_type(4))) unsigned short u16x4;

#define DEVINL static __device__ __forceinline__
#define MFMA __builtin_amdgcn_mfma_f32_16x16x32_bf16

DEVINL unsigned short f2bf(float f){
  union { float f; unsigned u; } v; v.f = f;
  unsigned r = v.u + 0x7FFFu + ((v.u >> 16) & 1u);   // RNE
  return (unsigned short)(r >> 16);
}
DEVINL float bf2f(unsigned short h){
  union { unsigned u; float f; } v; v.u = ((unsigned)h) << 16;
  return v.f;
}

// B=4, C=QK=V=512, L=4096
// ---------- per-(b,c) mean/rstd, ddof=1, +eps ----------
__global__ void rowstats_k(const float* __restrict__ x,
                           float* __restrict__ mean, float* __restrict__ rstd){
  int row = blockIdx.x;
  const float4* p = (const float4*)(x + (long)row * 4096);
  float s = 0.f, ss = 0.f;
  for (int i = threadIdx.x; i < 1024; i += 256){
    float4 v = p[i];
    s  += v.x + v.y + v.z + v.w;
    ss += v.x*v.x + v.y*v.y + v.z*v.z + v.w*v.w;
  }
  for (int o = 32; o > 0; o >>= 1){ s += __shfl_down(s, o); ss += __shfl_down(ss, o); }
  __shared__ float ls[4], lss[4];
  int wv = threadIdx.x >> 6;
  if ((threadIdx.x & 63) == 0){ ls[wv] = s; lss[wv] = ss; }
  __syncthreads();
  if (threadIdx.x == 0){
    s = ls[0]+ls[1]+ls[2]+ls[3]; ss = lss[0]+lss[1]+lss[2]+lss[3];
    float m = s * (1.f/4096.f);
    float var = (ss - s*m) * (1.f/4095.f);
    mean[row] = m;
    rstd[row] = 1.f / sqrtf(var + 1e-5f);
  }
}

// ---------- fold mvn into weights, split hi/lo ----------
__global__ void foldw_k(const float* __restrict__ w, const float* __restrict__ bias,
                        const float* __restrict__ mean, const float* __restrict__ rstd,
                        unsigned short* __restrict__ wh, unsigned short* __restrict__ wl,
                        float* __restrict__ biasp){
  int o = blockIdx.x;
  const float* wr = w + (long)o * 512;
  float part = 0.f;
  for (int c = threadIdx.x; c < 512; c += 256){
    float wv = wr[c] * rstd[c];
    unsigned short h = f2bf(wv);
    wh[(o<<9)+c] = h;
    wl[(o<<9)+c] = f2bf(wv - bf2f(h));
    part += wv * mean[c];
  }
  __shared__ float red[256];
  red[threadIdx.x] = part; __syncthreads();
  for (int st = 128; st > 0; st >>= 1){
    if (threadIdx.x < st) red[threadIdx.x] += red[threadIdx.x + st];
    __syncthreads();
  }
  if (threadIdx.x == 0) biasp[o] = bias[o] - red[0];
}

// ---------- plain split of h_w ----------
__global__ void wsplit_k(const float* __restrict__ w,
                         unsigned short* __restrict__ wh, unsigned short* __restrict__ wl){
  int i = blockIdx.x * 256 + threadIdx.x;
  float v = w[i];
  unsigned short h = f2bf(v);
  wh[i] = h; wl[i] = f2bf(v - bf2f(h));
}

// ---------- 3-term conv GEMM: Y[o][l] = sum_c W[o][c] X[c][l] + b[o] ----------
// MODE 0: write yh,yl transposed [l][512]   (Q, K)
// MODE 1: write vh,vl,v2h,v2l natural [512][l]   (V path, consistent squares)
template<int MODE>
__global__ __launch_bounds__(512) void conv3_k(
    const float* __restrict__ X,
    const unsigned short* __restrict__ Wh, const unsigned short* __restrict__ Wl,
    const float* __restrict__ biasp,
    unsigned short* __restrict__ oh, unsigned short* __restrict__ ol,
    unsigned short* __restrict__ o2h, unsigned short* __restrict__ o2l)
{
  int ob = blockIdx.y, lb = blockIdx.x;
  __shared__ unsigned short Xh[64][72], Xl[64][72];
  int tid = threadIdx.x, w = tid >> 6, lane = tid & 63, lr = lane & 15, lg = lane >> 4;
  const float* Xb = X + lb * 64;
  const unsigned short* WhB = Wh + (long)(ob*128 + w*16) * 512;
  const unsigned short* WlB = Wl + (long)(ob*128 + w*16) * 512;
  f32x4 acc[4] = {};
  int slq = tid & 63, sc0 = tid >> 6;
  for (int cb = 0; cb < 8; ++cb){
    __syncthreads();
    #pragma unroll
    for (int i = 0; i < 8; ++i){
      int c = sc0 + i*8;
      float x = Xb[((long)(cb*64 + c)) * 4096 + slq];
      unsigned short h = f2bf(x);
      Xh[slq][c] = h;
      Xl[slq][c] = f2bf(x - bf2f(h));
    }
    __syncthreads();
    #pragma unroll
    for (int kk = 0; kk < 2; ++kk){
      short8 ah = *(const short8*)(WhB + (long)lr*512 + cb*64 + kk*32 + lg*8);
      short8 al = *(const short8*)(WlB + (long)lr*512 + cb*64 + kk*32 + lg*8);
      #pragma unroll
      for (int ct = 0; ct < 4; ++ct){
        short8 bh = *(const short8*)(&Xh[ct*16 + lr][kk*32 + lg*8]);
        short8 bl = *(const short8*)(&Xl[ct*16 + lr][kk*32 + lg*8]);
        acc[ct] = MFMA(ah, bh, acc[ct], 0,0,0);
        acc[ct] = MFMA(al, bh, acc[ct], 0,0,0);
        acc[ct] = MFMA(ah, bl, acc[ct], 0,0,0);
      }
    }
  }
  int o4 = ob*128 + w*16 + lg*4;
  float bv[4];
  #pragma unroll
  for (int r = 0; r < 4; ++r) bv[r] = biasp[o4 + r];
  if (MODE == 0){
    #pragma unroll
    for (int ct = 0; ct < 4; ++ct){
      u16x4 ph, pl;
      #pragma unroll
      for (int r = 0; r < 4; ++r){
        float y = acc[ct][r] + bv[r];
        unsigned short h = f2bf(y);
        ph[r] = h; pl[r] = f2bf(y - bf2f(h));
      }
      long base = ((long)(lb*64 + ct*16 + lr)) * 512 + o4;
      *(u16x4*)(oh + base) = ph;
      *(u16x4*)(ol + base) = pl;
    }
  } else {
    #pragma unroll
    for (int ct = 0; ct < 4; ++ct){
      #pragma unroll
      for (int r = 0; r < 4; ++r){
        float y = acc[ct][r] + bv[r];
        unsigned short h = f2bf(y);
        float ve = bf2f(h);
        unsigned short l = f2bf(y - ve);
        ve += bf2f(l);
        float v2 = ve * ve;
        unsigned short h2 = f2bf(v2);
        unsigned short l2 = f2bf(v2 - bf2f(h2));
        long idx = ((long)(o4 + r)) * 4096 + lb*64 + ct*16 + lr;
        oh[idx] = h; ol[idx] = l; o2h[idx] = h2; o2l[idx] = l2;
      }
    }
  }
}

// ---------- 3-term S GEMM: S[q][k] = Q[q][:]·K[k][:], fp32 out ----------
__global__ __launch_bounds__(512) void sgemm3_k(
    const unsigned short* __restrict__ Qh, const unsigned short* __restrict__ Ql,
    const unsigned short* __restrict__ Kh, const unsigned short* __restrict__ Kl,
    float* __restrict__ S, int qbase)
{
  int bx = blockIdx.x, by = blockIdx.y;
  int q0g = qbase + bx*128, k0 = by*128;
  __shared__ unsigned short Qhs[128][72], Qls[128][72], Khs[128][72], Kls[128][72];
  int tid = threadIdx.x, w = tid >> 6, lane = tid & 63, lr = lane & 15, lg = lane >> 4;
  int wr = w & 1, wc = w >> 1;
  f32x4 acc[4][2] = {};
  for (int cb = 0; cb < 8; ++cb){
    __syncthreads();
    int c0 = cb*64;
    #pragma unroll
    for (int s = 0; s < 2; ++s){
      int slot = tid + s*512;
      int row = slot >> 3, cg = (slot & 7)*8;
      *(short8*)(&Qhs[row][cg]) = *(const short8*)(Qh + ((long)(q0g+row))*512 + c0 + cg);
      *(short8*)(&Qls[row][cg]) = *(const short8*)(Ql + ((long)(q0g+row))*512 + c0 + cg);
      *(short8*)(&Khs[row][cg]) = *(const short8*)(Kh + ((long)(k0+row))*512 + c0 + cg);
      *(short8*)(&Kls[row][cg]) = *(const short8*)(Kl + ((long)(k0+row))*512 + c0 + cg);
    }
    __syncthreads();
    #pragma unroll
    for (int kk = 0; kk < 2; ++kk){
      short8 bh[2], bl[2];
      #pragma unroll
      for (int bs = 0; bs < 2; ++bs){
        int krow = wc*32 + bs*16 + lr;
        bh[bs] = *(const short8*)(&Khs[krow][kk*32 + lg*8]);
        bl[bs] = *(const short8*)(&Kls[krow][kk*32 + lg*8]);
      }
      #pragma unroll
      for (int as = 0; as < 4; ++as){
        int qrow = wr*64 + as*16 + lr;
        short8 ah = *(const short8*)(&Qhs[qrow][kk*32 + lg*8]);
        short8 al = *(const short8*)(&Qls[qrow][kk*32 + lg*8]);
        #pragma unroll
        for (int bs = 0; bs < 2; ++bs){
          acc[as][bs] = MFMA(ah, bh[bs], acc[as][bs], 0,0,0);
          acc[as][bs] = MFMA(al, bh[bs], acc[as][bs], 0,0,0);
          acc[as][bs] = MFMA(ah, bl[bs], acc[as][bs], 0,0,0);
        }
      }
    }
  }
  #pragma unroll
  for (int as = 0; as < 4; ++as){
    #pragma unroll
    for (int bs = 0; bs < 2; ++bs){
      int q = bx*128 + wr*64 + as*16 + lg*4;      // chunk-local
      int k = k0 + wc*32 + bs*16 + lr;
      float* Sp = S + (long)q*4096 + k;
      #pragma unroll
      for (int r = 0; r < 4; ++r) Sp[(long)r*4096] = acc[as][bs][r];
    }
  }
}

// ---------- row softmax; P bf16 written in-place over S; exact renorm factor ----------
__global__ __launch_bounds__(256) void softmax_k(float* __restrict__ S, float* __restrict__ inv2){
  int row = blockIdx.x;
  float* Sr = S + (long)row * 4096;
  int t = threadIdx.x;
  f32x4 v[4];
  #pragma unroll
  for (int i = 0; i < 4; ++i) v[i] = *(const f32x4*)(Sr + t*4 + i*1024);
  float mx = v[0][0];
  #pragma unroll
  for (int i = 0; i < 4; ++i)
    #pragma unroll
    for (int j = 0; j < 4; ++j) mx = fmaxf(mx, v[i][j]);
  #pragma unroll
  for (int o = 32; o > 0; o >>= 1) mx = fmaxf(mx, __shfl_xor(mx, o));
  __shared__ float red[4];
  int wid = t >> 6;
  if ((t & 63) == 0) red[wid] = mx;
  __syncthreads();
  mx = fmaxf(fmaxf(red[0], red[1]), fmaxf(red[2], red[3]));
  __syncthreads();
  float p[16]; float d = 0.f;
  #pragma unroll
  for (int i = 0; i < 4; ++i)
    #pragma unroll
    for (int j = 0; j < 4; ++j){ float e = expf(v[i][j] - mx); p[i*4+j] = e; d += e; }
  #pragma unroll
  for (int o = 32; o > 0; o >>= 1) d += __shfl_xor(d, o);
  if ((t & 63) == 0) red[wid] = d;
  __syncthreads();
  d = red[0] + red[1] + red[2] + red[3];
  __syncthreads();
  float invd = 1.f / d;
  unsigned short pb[16]; float d2 = 0.f;
  #pragma unroll
  for (int i = 0; i < 16; ++i){ pb[i] = f2bf(p[i] * invd); d2 += bf2f(pb[i]); }
  #pragma unroll
  for (int o = 32; o > 0; o >>= 1) d2 += __shfl_xor(d2, o);
  if ((t & 63) == 0) red[wid] = d2;
  __syncthreads();
  if (t == 0) inv2[row] = 1.f / (red[0]+red[1]+red[2]+red[3]);
  unsigned short* Pr = (unsigned short*)Sr;
  #pragma unroll
  for (int i = 0; i < 4; ++i){
    u16x4 pk;
    #pragma unroll
    for (int j = 0; j < 4; ++j) pk[j] = pb[i*4+j];
    *(u16x4*)(Pr + t*4 + i*1024) = pk;
  }
}

// ---------- PV GEMM + epilogue: M,M2 -> Var -> out = sd*mvn(cx) + M ----------
__global__ __launch_bounds__(512) void pv_k(
    const float* __restrict__ Schunk,
    const unsigned short* __restrict__ vh, const unsigned short* __restrict__ vl,
    const unsigned short* __restrict__ v2h, const unsigned short* __restrict__ v2l,
    const float* __restrict__ inv2,
    const float* __restrict__ cx, const float* __restrict__ mcx, const float* __restrict__ rcx,
    float* __restrict__ outb, int qbase)
{
  int bx = blockIdx.x, by = blockIdx.y;
  int q0l = bx*128, vc0 = by*64;
  __shared__ unsigned short Ps[128][72];
  __shared__ unsigned short Vhs[64][72], Vls[64][72], V2hs[64][72], V2ls[64][72];
  int tid = threadIdx.x, w = tid >> 6, lane = tid & 63, lr = lane & 15, lg = lane >> 4;
  int wq = w & 3, wvc = w >> 2;
  f32x4 accM[2][2] = {}, accM2[2][2] = {};
  for (int kt = 0; kt < 64; ++kt){
    __syncthreads();
    int k0 = kt*64;
    #pragma unroll
    for (int s = 0; s < 2; ++s){
      int slot = tid + s*512;
      int row = slot >> 3, cg = (slot & 7)*8;
      const unsigned short* Pr = (const unsigned short*)(Schunk + (long)(q0l+row)*4096);
      *(short8*)(&Ps[row][cg]) = *(const short8*)(Pr + k0 + cg);
    }
    {
      int row = tid >> 3, cg = (tid & 7)*8;
      long gidx = (long)(vc0+row)*4096 + k0 + cg;
      *(short8*)(&Vhs[row][cg])  = *(const short8*)(vh + gidx);
      *(short8*)(&Vls[row][cg])  = *(const short8*)(vl + gidx);
      *(short8*)(&V2hs[row][cg]) = *(const short8*)(v2h + gidx);
      *(short8*)(&V2ls[row][cg]) = *(const short8*)(v2l + gidx);
    }
    __syncthreads();
    #pragma unroll
    for (int kk = 0; kk < 2; ++kk){
      short8 pa[2];
      #pragma unroll
      for (int as = 0; as < 2; ++as)
        pa[as] = *(const short8*)(&Ps[wq*32 + as*16 + lr][kk*32 + lg*8]);
      #pragma unroll
      for (int bs = 0; bs < 2; ++bs){
        int vrow = wvc*32 + bs*16 + lr;
        short8 fh  = *(const short8*)(&Vhs[vrow][kk*32 + lg*8]);
        short8 fl  = *(const short8*)(&Vls[vrow][kk*32 + lg*8]);
        short8 f2h = *(const short8*)(&V2hs[vrow][kk*32 + lg*8]);
        short8 f2l = *(const short8*)(&V2ls[vrow][kk*32 + lg*8]);
        #pragma unroll
        for (int as = 0; as < 2; ++as){
          accM[as][bs]  = MFMA(pa[as], fh,  accM[as][bs],  0,0,0);
          accM[as][bs]  = MFMA(pa[as], fl,  accM[as][bs],  0,0,0);
          accM2[as][bs] = MFMA(pa[as], f2h, accM2[as][bs], 0,0,0);
          accM2[as][bs] = MFMA(pa[as], f2l, accM2[as][bs], 0,0,0);
        }
      }
    }
  }
  #pragma unroll
  for (int as = 0; as < 2; ++as){
    int ql = q0l + wq*32 + as*16 + lg*4;
    int qg = qbase + ql;
    f32x4 iv = *(const f32x4*)(inv2 + ql);
    #pragma unroll
    for (int bs = 0; bs < 2; ++bs){
      int vc = vc0 + wvc*32 + bs*16 + lr;
      float mu = mcx[vc], rs = rcx[vc];
      const float* cxp = cx + (long)vc*4096 + qg;
      float* op = outb + (long)vc*4096 + qg;
      f32x4 cv = *(const f32x4*)cxp;
      f32x4 ov;
      #pragma unroll
      for (int r = 0; r < 4; ++r){
        float M  = accM[as][bs][r]  * iv[r];
        float M2 = accM2[as][bs][r] * iv[r];
        float var = M2 - M*M;
        float sd = sqrtf(fmaxf(var, 0.f));
        ov[r] = sd * (cv[r] - mu) * rs + M;
      }
      *(f32x4*)op = ov;
    }
  }
}

// ---------- launch ----------
extern "C" void kernel_launch(void* const* d_in, const int* in_sizes, int n_in,
                              void* d_out, int out_size, void* d_ws, size_t ws_size,
                              hipStream_t stream){
  const float* c_x  = (const float*)d_in[0];
  const float* s_x  = (const float*)d_in[1];
  const float* c_1x = (const float*)d_in[2];
  const float* s_1x = (const float*)d_in[3];
  const float* f_w  = (const float*)d_in[4];
  const float* f_b  = (const float*)d_in[5];
  const float* g_w  = (const float*)d_in[6];
  const float* g_b  = (const float*)d_in[7];
  const float* h_w  = (const float*)d_in[8];
  const float* h_b  = (const float*)d_in[9];
  float* out = (float*)d_out;

  char* ws = (char*)d_ws;
  size_t off = 0;
  auto alloc = [&](size_t bytes)->void*{
    void* p = ws + off; off += (bytes + 255) & ~(size_t)255; return p;
  };
  float* meanQ = (float*)alloc(2048*4); float* rstdQ = (float*)alloc(2048*4);
  float* meanK = (float*)alloc(2048*4); float* rstdK = (float*)alloc(2048*4);
  float* meanC = (float*)alloc(2048*4); float* rstdC = (float*)alloc(2048*4);
  float* biasF = (float*)alloc(512*4);  float* biasG = (float*)alloc(512*4);
  unsigned short* Wfh = (unsigned short*)alloc((size_t)512*512*2);
  unsigned short* Wfl = (unsigned short*)alloc((size_t)512*512*2);
  unsigned short* Wgh = (unsigned short*)alloc((size_t)512*512*2);
  unsigned short* Wgl = (unsigned short*)alloc((size_t)512*512*2);
  unsigned short* Whh = (unsigned short*)alloc((size_t)512*512*2);
  unsigned short* Whl = (unsigned short*)alloc((size_t)512*512*2);
  unsigned short* Qh = (unsigned short*)alloc((size_t)4096*512*2);
  unsigned short* Ql = (unsigned short*)alloc((size_t)4096*512*2);
  unsigned short* Kh = (unsigned short*)alloc((size_t)4096*512*2);
  unsigned short* Kl = (unsigned short*)alloc((size_t)4096*512*2);
  unsigned short* vh  = (unsigned short*)alloc((size_t)512*4096*2);
  unsigned short* vl  = (unsigned short*)alloc((size_t)512*4096*2);
  unsigned short* v2h = (unsigned short*)alloc((size_t)512*4096*2);
  unsigned short* v2l = (unsigned short*)alloc((size_t)512*4096*2);
  float* S    = (float*)alloc((size_t)2048*4096*4);   // chunk; P bf16 in-place
  float* inv2 = (float*)alloc(2048*4);
  // total ~70.4 MB

  rowstats_k<<<2048, 256, 0, stream>>>(c_1x, meanQ, rstdQ);
  rowstats_k<<<2048, 256, 0, stream>>>(s_1x, meanK, rstdK);
  rowstats_k<<<2048, 256, 0, stream>>>(c_x,  meanC, rstdC);
  wsplit_k<<<1024, 256, 0, stream>>>(h_w, Whh, Whl);

  for (int b = 0; b < 4; ++b){
    long xoff = (long)b * 512 * 4096;
    foldw_k<<<512, 256, 0, stream>>>(f_w, f_b, meanQ + b*512, rstdQ + b*512, Wfh, Wfl, biasF);
    foldw_k<<<512, 256, 0, stream>>>(g_w, g_b, meanK + b*512, rstdK + b*512, Wgh, Wgl, biasG);
    conv3_k<0><<<dim3(64,4), 512, 0, stream>>>(c_1x + xoff, Wfh, Wfl, biasF, Qh, Ql, nullptr, nullptr);
    conv3_k<0><<<dim3(64,4), 512, 0, stream>>>(s_1x + xoff, Wgh, Wgl, biasG, Kh, Kl, nullptr, nullptr);
    conv3_k<1><<<dim3(64,4), 512, 0, stream>>>(s_x + xoff, Whh, Whl, h_b, vh, vl, v2h, v2l);
    for (int ch = 0; ch < 2; ++ch){
      int qbase = ch * 2048;
      sgemm3_k<<<dim3(16,32), 512, 0, stream>>>(Qh, Ql, Kh, Kl, S, qbase);
      softmax_k<<<2048, 256, 0, stream>>>(S, inv2);
      pv_k<<<dim3(16,8), 512, 0, stream>>>(S, vh, vl, v2h, v2l, inv2,
                                           c_x + xoff, meanC + b*512, rstdC + b*512,
                                           out + xoff, qbase);
    }
  }
}

// Round 4
// 1104.150 us; speedup vs baseline: 1.4617x; 1.4617x over previous
//
#include <hip/hip_runtime.h>
#include <math.h>

typedef __attribute__((ext_vector_type(8))) short short8;    // 8 x bf16
typedef __attribute__((ext_vector_type(4))) float f32x4;
typedef __attribute__((ext_vector_type(4))) unsigned short u16x4;

#define DEVINL static __device__ __forceinline__
#define MFMA __builtin_amdgcn_mfma_f32_16x16x32_bf16

DEVINL unsigned short f2bf(float f){
  union { float f; unsigned u; } v; v.f = f;
  unsigned r = v.u + 0x7FFFu + ((v.u >> 16) & 1u);   // RNE
  return (unsigned short)(r >> 16);
}
DEVINL float bf2f(unsigned short h){
  union { unsigned u; float f; } v; v.u = ((unsigned)h) << 16;
  return v.f;
}

// B=4, C=QK=V=512, L=4096
__global__ void rowstats_k(const float* __restrict__ x,
                           float* __restrict__ mean, float* __restrict__ rstd){
  int row = blockIdx.x;
  const float4* p = (const float4*)(x + (long)row * 4096);
  float s = 0.f, ss = 0.f;
  for (int i = threadIdx.x; i < 1024; i += 256){
    float4 v = p[i];
    s  += v.x + v.y + v.z + v.w;
    ss += v.x*v.x + v.y*v.y + v.z*v.z + v.w*v.w;
  }
  for (int o = 32; o > 0; o >>= 1){ s += __shfl_down(s, o); ss += __shfl_down(ss, o); }
  __shared__ float ls[4], lss[4];
  int wv = threadIdx.x >> 6;
  if ((threadIdx.x & 63) == 0){ ls[wv] = s; lss[wv] = ss; }
  __syncthreads();
  if (threadIdx.x == 0){
    s = ls[0]+ls[1]+ls[2]+ls[3]; ss = lss[0]+lss[1]+lss[2]+lss[3];
    float m = s * (1.f/4096.f);
    float var = (ss - s*m) * (1.f/4095.f);
    mean[row] = m;
    rstd[row] = 1.f / sqrtf(var + 1e-5f);
  }
}

__global__ void foldw_k(const float* __restrict__ w, const float* __restrict__ bias,
                        const float* __restrict__ mean, const float* __restrict__ rstd,
                        unsigned short* __restrict__ wh, unsigned short* __restrict__ wl,
                        float* __restrict__ biasp){
  int o = blockIdx.x;
  const float* wr = w + (long)o * 512;
  float part = 0.f;
  for (int c = threadIdx.x; c < 512; c += 256){
    float wv = wr[c] * rstd[c];
    unsigned short h = f2bf(wv);
    wh[(o<<9)+c] = h;
    wl[(o<<9)+c] = f2bf(wv - bf2f(h));
    part += wv * mean[c];
  }
  __shared__ float red[256];
  red[threadIdx.x] = part; __syncthreads();
  for (int st = 128; st > 0; st >>= 1){
    if (threadIdx.x < st) red[threadIdx.x] += red[threadIdx.x + st];
    __syncthreads();
  }
  if (threadIdx.x == 0) biasp[o] = bias[o] - red[0];
}

__global__ void wsplit_k(const float* __restrict__ w,
                         unsigned short* __restrict__ wh, unsigned short* __restrict__ wl){
  int i = blockIdx.x * 256 + threadIdx.x;
  float v = w[i];
  unsigned short h = f2bf(v);
  wh[i] = h; wl[i] = f2bf(v - bf2f(h));
}

// ---------- 3-term conv GEMM ----------
template<int MODE>
__global__ __launch_bounds__(512) void conv3_k(
    const float* __restrict__ X,
    const unsigned short* __restrict__ Wh, const unsigned short* __restrict__ Wl,
    const float* __restrict__ biasp,
    unsigned short* __restrict__ oh, unsigned short* __restrict__ ol,
    unsigned short* __restrict__ o2h, unsigned short* __restrict__ o2l)
{
  int ob = blockIdx.y, lb = blockIdx.x;
  __shared__ unsigned short Xh[64][72], Xl[64][72];
  int tid = threadIdx.x, w = tid >> 6, lane = tid & 63, lr = lane & 15, lg = lane >> 4;
  const float* Xb = X + lb * 64;
  const unsigned short* WhB = Wh + (long)(ob*128 + w*16) * 512;
  const unsigned short* WlB = Wl + (long)(ob*128 + w*16) * 512;
  f32x4 acc[4] = {};
  int slq = tid & 63, sc0 = tid >> 6;
  for (int cb = 0; cb < 8; ++cb){
    __syncthreads();
    #pragma unroll
    for (int i = 0; i < 8; ++i){
      int c = sc0 + i*8;
      float x = Xb[((long)(cb*64 + c)) * 4096 + slq];
      unsigned short h = f2bf(x);
      Xh[slq][c] = h;
      Xl[slq][c] = f2bf(x - bf2f(h));
    }
    __syncthreads();
    #pragma unroll
    for (int kk = 0; kk < 2; ++kk){
      short8 ah = *(const short8*)(WhB + (long)lr*512 + cb*64 + kk*32 + lg*8);
      short8 al = *(const short8*)(WlB + (long)lr*512 + cb*64 + kk*32 + lg*8);
      #pragma unroll
      for (int ct = 0; ct < 4; ++ct){
        short8 bh = *(const short8*)(&Xh[ct*16 + lr][kk*32 + lg*8]);
        short8 bl = *(const short8*)(&Xl[ct*16 + lr][kk*32 + lg*8]);
        acc[ct] = MFMA(ah, bh, acc[ct], 0,0,0);
        acc[ct] = MFMA(al, bh, acc[ct], 0,0,0);
        acc[ct] = MFMA(ah, bl, acc[ct], 0,0,0);
      }
    }
  }
  int o4 = ob*128 + w*16 + lg*4;
  float bv[4];
  #pragma unroll
  for (int r = 0; r < 4; ++r) bv[r] = biasp[o4 + r];
  if (MODE == 0){
    #pragma unroll
    for (int ct = 0; ct < 4; ++ct){
      u16x4 ph, pl;
      #pragma unroll
      for (int r = 0; r < 4; ++r){
        float y = acc[ct][r] + bv[r];
        unsigned short h = f2bf(y);
        ph[r] = h; pl[r] = f2bf(y - bf2f(h));
      }
      long base = ((long)(lb*64 + ct*16 + lr)) * 512 + o4;
      *(u16x4*)(oh + base) = ph;
      *(u16x4*)(ol + base) = pl;
    }
  } else {
    #pragma unroll
    for (int ct = 0; ct < 4; ++ct){
      #pragma unroll
      for (int r = 0; r < 4; ++r){
        float y = acc[ct][r] + bv[r];
        unsigned short h = f2bf(y);
        float ve = bf2f(h);
        unsigned short l = f2bf(y - ve);
        ve += bf2f(l);
        float v2 = ve * ve;
        unsigned short h2 = f2bf(v2);
        unsigned short l2 = f2bf(v2 - bf2f(h2));
        long idx = ((long)(o4 + r)) * 4096 + lb*64 + ct*16 + lr;
        oh[idx] = h; ol[idx] = l; o2h[idx] = h2; o2l[idx] = l2;
      }
    }
  }
}

// ---------- 3-term S GEMM ----------
__global__ __launch_bounds__(512) void sgemm3_k(
    const unsigned short* __restrict__ Qh, const unsigned short* __restrict__ Ql,
    const unsigned short* __restrict__ Kh, const unsigned short* __restrict__ Kl,
    float* __restrict__ S, int qbase)
{
  int bx = blockIdx.x, by = blockIdx.y;
  int q0g = qbase + bx*128, k0 = by*128;
  __shared__ unsigned short Qhs[128][72], Qls[128][72], Khs[128][72], Kls[128][72];
  int tid = threadIdx.x, w = tid >> 6, lane = tid & 63, lr = lane & 15, lg = lane >> 4;
  int wr = w & 1, wc = w >> 1;
  f32x4 acc[4][2] = {};
  for (int cb = 0; cb < 8; ++cb){
    __syncthreads();
    int c0 = cb*64;
    #pragma unroll
    for (int s = 0; s < 2; ++s){
      int slot = tid + s*512;
      int row = slot >> 3, cg = (slot & 7)*8;
      *(short8*)(&Qhs[row][cg]) = *(const short8*)(Qh + ((long)(q0g+row))*512 + c0 + cg);
      *(short8*)(&Qls[row][cg]) = *(const short8*)(Ql + ((long)(q0g+row))*512 + c0 + cg);
      *(short8*)(&Khs[row][cg]) = *(const short8*)(Kh + ((long)(k0+row))*512 + c0 + cg);
      *(short8*)(&Kls[row][cg]) = *(const short8*)(Kl + ((long)(k0+row))*512 + c0 + cg);
    }
    __syncthreads();
    #pragma unroll
    for (int kk = 0; kk < 2; ++kk){
      short8 bh[2], bl[2];
      #pragma unroll
      for (int bs = 0; bs < 2; ++bs){
        int krow = wc*32 + bs*16 + lr;
        bh[bs] = *(const short8*)(&Khs[krow][kk*32 + lg*8]);
        bl[bs] = *(const short8*)(&Kls[krow][kk*32 + lg*8]);
      }
      #pragma unroll
      for (int as = 0; as < 4; ++as){
        int qrow = wr*64 + as*16 + lr;
        short8 ah = *(const short8*)(&Qhs[qrow][kk*32 + lg*8]);
        short8 al = *(const short8*)(&Qls[qrow][kk*32 + lg*8]);
        #pragma unroll
        for (int bs = 0; bs < 2; ++bs){
          acc[as][bs] = MFMA(ah, bh[bs], acc[as][bs], 0,0,0);
          acc[as][bs] = MFMA(al, bh[bs], acc[as][bs], 0,0,0);
          acc[as][bs] = MFMA(ah, bl[bs], acc[as][bs], 0,0,0);
        }
      }
    }
  }
  #pragma unroll
  for (int as = 0; as < 4; ++as){
    #pragma unroll
    for (int bs = 0; bs < 2; ++bs){
      int q = bx*128 + wr*64 + as*16 + lg*4;
      int k = k0 + wc*32 + bs*16 + lr;
      float* Sp = S + (long)q*4096 + k;
      #pragma unroll
      for (int r = 0; r < 4; ++r) Sp[(long)r*4096] = acc[as][bs][r];
    }
  }
}

// ---------- row softmax: read fp32 S chunk row, write bf16 P (pitch param) ----------
__global__ __launch_bounds__(256) void softmax_k(const float* __restrict__ S,
                                                 unsigned short* __restrict__ Pb, long pitch,
                                                 int row0, float* __restrict__ inv2){
  int row = blockIdx.x;
  const float* Sr = S + (long)row * 4096;
  int t = threadIdx.x;
  f32x4 v[4];
  #pragma unroll
  for (int i = 0; i < 4; ++i) v[i] = *(const f32x4*)(Sr + t*4 + i*1024);
  float mx = v[0][0];
  #pragma unroll
  for (int i = 0; i < 4; ++i)
    #pragma unroll
    for (int j = 0; j < 4; ++j) mx = fmaxf(mx, v[i][j]);
  #pragma unroll
  for (int o = 32; o > 0; o >>= 1) mx = fmaxf(mx, __shfl_xor(mx, o));
  __shared__ float red[4];
  int wid = t >> 6;
  if ((t & 63) == 0) red[wid] = mx;
  __syncthreads();
  mx = fmaxf(fmaxf(red[0], red[1]), fmaxf(red[2], red[3]));
  __syncthreads();
  float p[16]; float d = 0.f;
  #pragma unroll
  for (int i = 0; i < 4; ++i)
    #pragma unroll
    for (int j = 0; j < 4; ++j){ float e = expf(v[i][j] - mx); p[i*4+j] = e; d += e; }
  #pragma unroll
  for (int o = 32; o > 0; o >>= 1) d += __shfl_xor(d, o);
  if ((t & 63) == 0) red[wid] = d;
  __syncthreads();
  d = red[0] + red[1] + red[2] + red[3];
  __syncthreads();
  float invd = 1.f / d;
  unsigned short pb[16]; float d2 = 0.f;
  #pragma unroll
  for (int i = 0; i < 16; ++i){ pb[i] = f2bf(p[i] * invd); d2 += bf2f(pb[i]); }
  #pragma unroll
  for (int o = 32; o > 0; o >>= 1) d2 += __shfl_xor(d2, o);
  if ((t & 63) == 0) red[wid] = d2;
  __syncthreads();
  if (t == 0) inv2[row0 + row] = 1.f / (red[0]+red[1]+red[2]+red[3]);
  unsigned short* Pr = Pb + (long)(row0 + row) * pitch;
  #pragma unroll
  for (int i = 0; i < 4; ++i){
    u16x4 pk;
    #pragma unroll
    for (int j = 0; j < 4; ++j) pk[j] = pb[i*4+j];
    *(u16x4*)(Pr + t*4 + i*1024) = pk;
  }
}

// ---------- pipelined PV GEMM + epilogue ----------
// block: 512 thr, tile 128q x 64vc over k=4096; waves: s=w&1 (k-substep split),
// wv=(w>>1)&1 (vc half), wq=w>>2 (q half). 2-phase double-buffered LDS.
// All LDS carved from ONE block so the float scratch aliasing is layout-safe.
__global__ __launch_bounds__(512, 2) void pv2_k(
    const unsigned short* __restrict__ P, long ppitch,
    const unsigned short* __restrict__ vh, const unsigned short* __restrict__ vl,
    const unsigned short* __restrict__ v2h, const unsigned short* __restrict__ v2l,
    const float* __restrict__ inv2,
    const float* __restrict__ cx, const float* __restrict__ mcx, const float* __restrict__ rcx,
    float* __restrict__ outb, int qP_base, int qG_base)
{
  __shared__ __align__(16) char smem[110592];           // 108 KB
  typedef unsigned short (*PlT)[128][72];               // Pl[2][128][72] : 36864 B
  typedef unsigned short (*VlT)[4][64][72];             // Vl[2][4][64][72] : 73728 B
  PlT Pl = (PlT)smem;
  VlT Vl = (VlT)(smem + 36864);
  float* R = (float*)smem;                              // scratch: 27648 floats, max used 16892

  int tid = threadIdx.x;
  int l = tid & 63, w = tid >> 6;
  int s = w & 1, wv = (w >> 1) & 1, wq = w >> 2;
  int lr = l & 15, lg = l >> 4;
  int qP0 = qP_base + blockIdx.x*128, qG0 = qG_base + blockIdx.x*128;
  int vc0 = blockIdx.y*64;

  int rowA = tid >> 3, c8 = (tid & 7)*8;
  const unsigned short* pgA = P + (long)(qP0 + rowA)*ppitch + c8;
  const unsigned short* pgB = pgA + (long)64*ppitch;
  long vgo = (long)(vc0 + rowA)*4096 + c8;
  const unsigned short* vg0 = vh  + vgo;
  const unsigned short* vg1 = vl  + vgo;
  const unsigned short* vg2 = v2h + vgo;
  const unsigned short* vg3 = v2l + vgo;

  f32x4 accM[4][2] = {}, acc2[4][2] = {};
  short8 rp0, rp1, rv0, rv1, rv2, rv3;

  // prologue: tile 0
  rp0 = *(const short8*)(pgA);
  rp1 = *(const short8*)(pgB);
  rv0 = *(const short8*)(vg0); rv1 = *(const short8*)(vg1);
  rv2 = *(const short8*)(vg2); rv3 = *(const short8*)(vg3);
  *(short8*)&Pl[0][rowA][c8] = rp0;
  *(short8*)&Pl[0][rowA+64][c8] = rp1;
  *(short8*)&Vl[0][0][rowA][c8] = rv0;
  *(short8*)&Vl[0][1][rowA][c8] = rv1;
  *(short8*)&Vl[0][2][rowA][c8] = rv2;
  *(short8*)&Vl[0][3][rowA][c8] = rv3;
  __syncthreads();

  int cur = 0;
  int kc = s*32 + lg*8;     // this wave's k-substep columns within a 64-k tile
  for (int t = 0; t < 64; ++t){
    if (t < 63){
      long ko = (long)(t+1)*64;
      rp0 = *(const short8*)(pgA + ko);
      rp1 = *(const short8*)(pgB + ko);
      rv0 = *(const short8*)(vg0 + ko);
      rv1 = *(const short8*)(vg1 + ko);
      rv2 = *(const short8*)(vg2 + ko);
      rv3 = *(const short8*)(vg3 + ko);
    }
    // compute from buf[cur]: 12 ds_read_b128 + 32 MFMA per wave
    short8 fh[2], fl2[2], f2h[2], f2l[2];
    #pragma unroll
    for (int bs = 0; bs < 2; ++bs){
      int vrow = wv*32 + bs*16 + lr;
      fh[bs]  = *(const short8*)(&Vl[cur][0][vrow][kc]);
      fl2[bs] = *(const short8*)(&Vl[cur][1][vrow][kc]);
      f2h[bs] = *(const short8*)(&Vl[cur][2][vrow][kc]);
      f2l[bs] = *(const short8*)(&Vl[cur][3][vrow][kc]);
    }
    #pragma unroll
    for (int aq = 0; aq < 4; ++aq){
      short8 pa = *(const short8*)(&Pl[cur][wq*64 + aq*16 + lr][kc]);
      #pragma unroll
      for (int bs = 0; bs < 2; ++bs){
        accM[aq][bs] = MFMA(pa, fh[bs],  accM[aq][bs], 0,0,0);
        accM[aq][bs] = MFMA(pa, fl2[bs], accM[aq][bs], 0,0,0);
        acc2[aq][bs] = MFMA(pa, f2h[bs], acc2[aq][bs], 0,0,0);
        acc2[aq][bs] = MFMA(pa, f2l[bs], acc2[aq][bs], 0,0,0);
      }
    }
    if (t < 63){
      int nb = cur ^ 1;
      *(short8*)&Pl[nb][rowA][c8] = rp0;
      *(short8*)&Pl[nb][rowA+64][c8] = rp1;
      *(short8*)&Vl[nb][0][rowA][c8] = rv0;
      *(short8*)&Vl[nb][1][rowA][c8] = rv1;
      *(short8*)&Vl[nb][2][rowA][c8] = rv2;
      *(short8*)&Vl[nb][3][rowA][c8] = rv3;
    }
    __syncthreads();
    cur ^= 1;
  }

  // ---- k-substep reduce: s=1 waves dump, s=0 partners add ----
  if (s == 1){
    float* Rb = R + (w>>1)*4096 + l*64;
    #pragma unroll
    for (int aq = 0; aq < 4; ++aq)
      #pragma unroll
      for (int bs = 0; bs < 2; ++bs)
        #pragma unroll
        for (int r = 0; r < 4; ++r){
          Rb[(aq*2+bs)*4 + r]      = accM[aq][bs][r];
          Rb[32 + (aq*2+bs)*4 + r] = acc2[aq][bs][r];
        }
  }
  __syncthreads();
  if (s == 0){
    const float* Rb = R + (w>>1)*4096 + l*64;
    #pragma unroll
    for (int aq = 0; aq < 4; ++aq)
      #pragma unroll
      for (int bs = 0; bs < 2; ++bs)
        #pragma unroll
        for (int r = 0; r < 4; ++r){
          accM[aq][bs][r] += Rb[(aq*2+bs)*4 + r];
          acc2[aq][bs][r] += Rb[32 + (aq*2+bs)*4 + r];
        }
  }
  __syncthreads();
  // ---- transpose to LDS: Tm/T2 [vc 64][q 128+pad4] ----
  float* Tm = R;
  float* T2 = R + 64*132;
  if (s == 0){
    #pragma unroll
    for (int aq = 0; aq < 4; ++aq)
      #pragma unroll
      for (int bs = 0; bs < 2; ++bs){
        int vcl = wv*32 + bs*16 + lr;
        int ql = wq*64 + aq*16 + lg*4;
        #pragma unroll
        for (int r = 0; r < 4; ++r){
          Tm[vcl*132 + ql + r] = accM[aq][bs][r];
          T2[vcl*132 + ql + r] = acc2[aq][bs][r];
        }
      }
  }
  __syncthreads();
  // ---- blend + coalesced store ----
  #pragma unroll
  for (int p = 0; p < 4; ++p){
    int chunk = tid + p*512;
    int row = chunk >> 5, c4 = (chunk & 31)*4;
    float mu = mcx[vc0 + row], rs = rcx[vc0 + row];
    f32x4 tm = *(const f32x4*)&Tm[row*132 + c4];
    f32x4 t2 = *(const f32x4*)&T2[row*132 + c4];
    f32x4 iv = *(const f32x4*)&inv2[qP0 + c4];
    f32x4 cv = *(const f32x4*)&cx[(long)(vc0+row)*4096 + qG0 + c4];
    f32x4 ov;
    #pragma unroll
    for (int j = 0; j < 4; ++j){
      float M = tm[j]*iv[j], M2 = t2[j]*iv[j];
      float var = M2 - M*M;
      float sd = sqrtf(fmaxf(var, 0.f));
      ov[j] = sd*(cv[j]-mu)*rs + M;
    }
    *(f32x4*)&outb[(long)(vc0+row)*4096 + qG0 + c4] = ov;
  }
}

// ---------- launch ----------
extern "C" void kernel_launch(void* const* d_in, const int* in_sizes, int n_in,
                              void* d_out, int out_size, void* d_ws, size_t ws_size,
                              hipStream_t stream){
  const float* c_x  = (const float*)d_in[0];
  const float* s_x  = (const float*)d_in[1];
  const float* c_1x = (const float*)d_in[2];
  const float* s_1x = (const float*)d_in[3];
  const float* f_w  = (const float*)d_in[4];
  const float* f_b  = (const float*)d_in[5];
  const float* g_w  = (const float*)d_in[6];
  const float* g_b  = (const float*)d_in[7];
  const float* h_w  = (const float*)d_in[8];
  const float* h_b  = (const float*)d_in[9];
  float* out = (float*)d_out;

  char* ws = (char*)d_ws;
  size_t off = 0;
  auto alloc = [&](size_t bytes)->void*{
    void* p = ws + off; off += (bytes + 255) & ~(size_t)255; return p;
  };
  float* meanQ = (float*)alloc(2048*4); float* rstdQ = (float*)alloc(2048*4);
  float* meanK = (float*)alloc(2048*4); float* rstdK = (float*)alloc(2048*4);
  float* meanC = (float*)alloc(2048*4); float* rstdC = (float*)alloc(2048*4);
  float* biasF = (float*)alloc(512*4);  float* biasG = (float*)alloc(512*4);
  unsigned short* Wfh = (unsigned short*)alloc((size_t)512*512*2);
  unsigned short* Wfl = (unsigned short*)alloc((size_t)512*512*2);
  unsigned short* Wgh = (unsigned short*)alloc((size_t)512*512*2);
  unsigned short* Wgl = (unsigned short*)alloc((size_t)512*512*2);
  unsigned short* Whh = (unsigned short*)alloc((size_t)512*512*2);
  unsigned short* Whl = (unsigned short*)alloc((size_t)512*512*2);
  unsigned short* Qh = (unsigned short*)alloc((size_t)4096*512*2);
  unsigned short* Ql = (unsigned short*)alloc((size_t)4096*512*2);
  unsigned short* Kh = (unsigned short*)alloc((size_t)4096*512*2);
  unsigned short* Kl = (unsigned short*)alloc((size_t)4096*512*2);
  unsigned short* vh  = (unsigned short*)alloc((size_t)512*4096*2);
  unsigned short* vl  = (unsigned short*)alloc((size_t)512*4096*2);
  unsigned short* v2h = (unsigned short*)alloc((size_t)512*4096*2);
  unsigned short* v2l = (unsigned short*)alloc((size_t)512*4096*2);
  float* S    = (float*)alloc((size_t)2048*4096*4);   // fp32 S chunk
  float* inv2 = (float*)alloc(4096*4);

  // mode A if ws can hold a full-batch bf16 P (32 MB)
  size_t pbytes = (size_t)4096*4096*2;
  bool bigP = (off + pbytes + 256 <= ws_size);
  unsigned short* Pb; long ppitch;
  if (bigP){ Pb = (unsigned short*)alloc(pbytes); ppitch = 4096; }
  else     { Pb = (unsigned short*)S;             ppitch = 8192; }

  rowstats_k<<<2048, 256, 0, stream>>>(c_1x, meanQ, rstdQ);
  rowstats_k<<<2048, 256, 0, stream>>>(s_1x, meanK, rstdK);
  rowstats_k<<<2048, 256, 0, stream>>>(c_x,  meanC, rstdC);
  wsplit_k<<<1024, 256, 0, stream>>>(h_w, Whh, Whl);

  for (int b = 0; b < 4; ++b){
    long xoff = (long)b * 512 * 4096;
    foldw_k<<<512, 256, 0, stream>>>(f_w, f_b, meanQ + b*512, rstdQ + b*512, Wfh, Wfl, biasF);
    foldw_k<<<512, 256, 0, stream>>>(g_w, g_b, meanK + b*512, rstdK + b*512, Wgh, Wgl, biasG);
    conv3_k<0><<<dim3(64,4), 512, 0, stream>>>(c_1x + xoff, Wfh, Wfl, biasF, Qh, Ql, nullptr, nullptr);
    conv3_k<0><<<dim3(64,4), 512, 0, stream>>>(s_1x + xoff, Wgh, Wgl, biasG, Kh, Kl, nullptr, nullptr);
    conv3_k<1><<<dim3(64,4), 512, 0, stream>>>(s_x + xoff, Whh, Whl, h_b, vh, vl, v2h, v2l);
    if (bigP){
      for (int ch = 0; ch < 2; ++ch){
        int qbase = ch * 2048;
        sgemm3_k<<<dim3(16,32), 512, 0, stream>>>(Qh, Ql, Kh, Kl, S, qbase);
        softmax_k<<<2048, 256, 0, stream>>>(S, Pb, 4096, qbase, inv2);
      }
      pv2_k<<<dim3(32,8), 512, 0, stream>>>(Pb, 4096, vh, vl, v2h, v2l, inv2,
                                            c_x + xoff, meanC + b*512, rstdC + b*512,
                                            out + xoff, 0, 0);
    } else {
      for (int ch = 0; ch < 2; ++ch){
        int qbase = ch * 2048;
        sgemm3_k<<<dim3(16,32), 512, 0, stream>>>(Qh, Ql, Kh, Kl, S, qbase);
        softmax_k<<<2048, 256, 0, stream>>>(S, Pb, 8192, 0, inv2);
        pv2_k<<<dim3(16,8), 512, 0, stream>>>(Pb, 8192, vh, vl, v2h, v2l, inv2,
                                              c_x + xoff, meanC + b*512, rstdC + b*512,
                                              out + xoff, 0, qbase);
      }
    }
  }
}

// Round 5
// 827.339 us; speedup vs baseline: 1.9507x; 1.3346x over previous
//
#include <hip/hip_runtime.h>
#include <math.h>

typedef __attribute__((ext_vector_type(8))) short short8;    // 8 x bf16
typedef __attribute__((ext_vector_type(4))) float f32x4;
typedef __attribute__((ext_vector_type(4))) unsigned short u16x4;

#define DEVINL static __device__ __forceinline__
#define MFMA __builtin_amdgcn_mfma_f32_16x16x32_bf16

DEVINL unsigned short f2bf(float f){
  union { float f; unsigned u; } v; v.f = f;
  unsigned r = v.u + 0x7FFFu + ((v.u >> 16) & 1u);   // RNE
  return (unsigned short)(r >> 16);
}
DEVINL float bf2f(unsigned short h){
  union { unsigned u; float f; } v; v.u = ((unsigned)h) << 16;
  return v.f;
}

// B=4, C=QK=V=512, L=4096
__global__ void rowstats_k(const float* __restrict__ x,
                           float* __restrict__ mean, float* __restrict__ rstd){
  int row = blockIdx.x;
  const float4* p = (const float4*)(x + (long)row * 4096);
  float s = 0.f, ss = 0.f;
  for (int i = threadIdx.x; i < 1024; i += 256){
    float4 v = p[i];
    s  += v.x + v.y + v.z + v.w;
    ss += v.x*v.x + v.y*v.y + v.z*v.z + v.w*v.w;
  }
  for (int o = 32; o > 0; o >>= 1){ s += __shfl_down(s, o); ss += __shfl_down(ss, o); }
  __shared__ float ls[4], lss[4];
  int wv = threadIdx.x >> 6;
  if ((threadIdx.x & 63) == 0){ ls[wv] = s; lss[wv] = ss; }
  __syncthreads();
  if (threadIdx.x == 0){
    s = ls[0]+ls[1]+ls[2]+ls[3]; ss = lss[0]+lss[1]+lss[2]+lss[3];
    float m = s * (1.f/4096.f);
    float var = (ss - s*m) * (1.f/4095.f);
    mean[row] = m;
    rstd[row] = 1.f / sqrtf(var + 1e-5f);
  }
}

__global__ void foldw_k(const float* __restrict__ w, const float* __restrict__ bias,
                        const float* __restrict__ mean, const float* __restrict__ rstd,
                        unsigned short* __restrict__ wh, unsigned short* __restrict__ wl,
                        float* __restrict__ biasp){
  int o = blockIdx.x;
  const float* wr = w + (long)o * 512;
  float part = 0.f;
  for (int c = threadIdx.x; c < 512; c += 256){
    float wv = wr[c] * rstd[c];
    unsigned short h = f2bf(wv);
    wh[(o<<9)+c] = h;
    wl[(o<<9)+c] = f2bf(wv - bf2f(h));
    part += wv * mean[c];
  }
  __shared__ float red[256];
  red[threadIdx.x] = part; __syncthreads();
  for (int st = 128; st > 0; st >>= 1){
    if (threadIdx.x < st) red[threadIdx.x] += red[threadIdx.x + st];
    __syncthreads();
  }
  if (threadIdx.x == 0) biasp[o] = bias[o] - red[0];
}

__global__ void wsplit_k(const float* __restrict__ w,
                         unsigned short* __restrict__ wh, unsigned short* __restrict__ wl){
  int i = blockIdx.x * 256 + threadIdx.x;
  float v = w[i];
  unsigned short h = f2bf(v);
  wh[i] = h; wl[i] = f2bf(v - bf2f(h));
}

// ---------- 3-term conv GEMM, pipelined ----------
// X staged transpose-in-register: coalesced float loads -> short8 LDS writes.
// W fragments prefetched to regs one K-step ahead. X double-buffered, 2-deep.
template<int MODE>
__global__ __launch_bounds__(512) void conv3_k(
    const float* __restrict__ X,
    const unsigned short* __restrict__ Wh, const unsigned short* __restrict__ Wl,
    const float* __restrict__ biasp,
    unsigned short* __restrict__ oh, unsigned short* __restrict__ ol,
    unsigned short* __restrict__ o2h, unsigned short* __restrict__ o2l)
{
  int ob = blockIdx.y, lb = blockIdx.x;
  __shared__ __align__(16) char csm[36864];
  typedef unsigned short (*XT)[64][72];
  XT Xh = (XT)csm;                 // [2][64][72]
  XT Xl = (XT)(csm + 18432);       // [2][64][72]

  int tid = threadIdx.x, w = tid >> 6, lane = tid & 63, lr = lane & 15, lg = lane >> 4;
  const unsigned short* WhB = Wh + (long)(ob*128 + w*16) * 512;
  const unsigned short* WlB = Wl + (long)(ob*128 + w*16) * 512;
  int sl = tid & 63, scg = tid >> 6;
  const float* Xg = X + (long)(scg*8)*4096 + lb*64 + sl;

  f32x4 acc[4] = {};
  float fA[8], fB[8];
  short8 wA0, wA1, wA2, wA3, wB0, wB1, wB2, wB3;

#define CV_XLOAD(F, CB) { _Pragma("unroll") for (int j=0;j<8;++j) F[j] = Xg[(long)((CB)*64 + j)*4096]; }
#define CV_XWRITE(BUF, F) { short8 hv, lv; _Pragma("unroll") for (int j=0;j<8;++j){ \
    unsigned short h_ = f2bf(F[j]); hv[j] = (short)h_; lv[j] = (short)f2bf(F[j] - bf2f(h_)); } \
    *(short8*)&Xh[BUF][sl][scg*8] = hv; *(short8*)&Xl[BUF][sl][scg*8] = lv; }
#define CV_WLOAD(W0,W1,W2,W3, CB) { \
    W0 = *(const short8*)(WhB + (long)lr*512 + (CB)*64 + lg*8); \
    W1 = *(const short8*)(WhB + (long)lr*512 + (CB)*64 + 32 + lg*8); \
    W2 = *(const short8*)(WlB + (long)lr*512 + (CB)*64 + lg*8); \
    W3 = *(const short8*)(WlB + (long)lr*512 + (CB)*64 + 32 + lg*8); }
#define CV_COMPUTE(BUF, W0,W1,W2,W3) { \
    _Pragma("unroll") for (int ct=0;ct<4;++ct){ \
      short8 bh = *(const short8*)&Xh[BUF][ct*16+lr][lg*8]; \
      short8 bl = *(const short8*)&Xl[BUF][ct*16+lr][lg*8]; \
      acc[ct] = MFMA(W0, bh, acc[ct], 0,0,0); \
      acc[ct] = MFMA(W2, bh, acc[ct], 0,0,0); \
      acc[ct] = MFMA(W0, bl, acc[ct], 0,0,0); } \
    _Pragma("unroll") for (int ct=0;ct<4;++ct){ \
      short8 bh = *(const short8*)&Xh[BUF][ct*16+lr][32+lg*8]; \
      short8 bl = *(const short8*)&Xl[BUF][ct*16+lr][32+lg*8]; \
      acc[ct] = MFMA(W1, bh, acc[ct], 0,0,0); \
      acc[ct] = MFMA(W3, bh, acc[ct], 0,0,0); \
      acc[ct] = MFMA(W1, bl, acc[ct], 0,0,0); } }

  CV_XLOAD(fA, 0); CV_XWRITE(0, fA);
  CV_XLOAD(fA, 1);
  CV_WLOAD(wA0,wA1,wA2,wA3, 0);
  __syncthreads();
  for (int cb = 0; cb < 8; cb += 2){
    if (cb+2 < 8) CV_XLOAD(fB, cb+2);
    CV_WLOAD(wB0,wB1,wB2,wB3, cb+1);
    CV_COMPUTE(0, wA0,wA1,wA2,wA3);
    CV_XWRITE(1, fA);
    __syncthreads();
    if (cb+3 < 8) CV_XLOAD(fA, cb+3);
    if (cb+2 < 8) CV_WLOAD(wA0,wA1,wA2,wA3, cb+2);
    CV_COMPUTE(1, wB0,wB1,wB2,wB3);
    if (cb+2 < 8) CV_XWRITE(0, fB);
    __syncthreads();
  }

  int o4 = ob*128 + w*16 + lg*4;
  float bv[4];
  #pragma unroll
  for (int r = 0; r < 4; ++r) bv[r] = biasp[o4 + r];
  if (MODE == 0){
    #pragma unroll
    for (int ct = 0; ct < 4; ++ct){
      u16x4 ph, pl;
      #pragma unroll
      for (int r = 0; r < 4; ++r){
        float y = acc[ct][r] + bv[r];
        unsigned short h = f2bf(y);
        ph[r] = h; pl[r] = f2bf(y - bf2f(h));
      }
      long base = ((long)(lb*64 + ct*16 + lr)) * 512 + o4;
      *(u16x4*)(oh + base) = ph;
      *(u16x4*)(ol + base) = pl;
    }
  } else {
    unsigned short sh_[16], sl_[16], s2h_[16], s2l_[16];
    #pragma unroll
    for (int ct = 0; ct < 4; ++ct)
      #pragma unroll
      for (int r = 0; r < 4; ++r){
        float y = acc[ct][r] + bv[r];
        unsigned short h = f2bf(y);
        float ve = bf2f(h);
        unsigned short l = f2bf(y - ve);
        ve += bf2f(l);
        float v2 = ve * ve;
        unsigned short h2 = f2bf(v2);
        unsigned short l2 = f2bf(v2 - bf2f(h2));
        sh_[ct*4+r] = h; sl_[ct*4+r] = l; s2h_[ct*4+r] = h2; s2l_[ct*4+r] = l2;
      }
    unsigned short* T = (unsigned short*)csm;   // [128][72]
#define CV_STORE(ARR, DST) { \
    __syncthreads(); \
    _Pragma("unroll") for (int ct=0;ct<4;++ct) \
      _Pragma("unroll") for (int r=0;r<4;++r) \
        T[(w*16+lg*4+r)*72 + ct*16+lr] = ARR[ct*4+r]; \
    __syncthreads(); \
    _Pragma("unroll") for (int s_=0;s_<2;++s_){ \
      int slot = tid + s_*512; int row = slot>>3, ch=(slot&7)*8; \
      *(short8*)(DST + (long)(ob*128+row)*4096 + lb*64 + ch) = *(const short8*)&T[row*72+ch]; } }
    CV_STORE(sh_,  oh);
    CV_STORE(sl_,  ol);
    CV_STORE(s2h_, o2h);
    CV_STORE(s2l_, o2l);
#undef CV_STORE
  }
#undef CV_XLOAD
#undef CV_XWRITE
#undef CV_WLOAD
#undef CV_COMPUTE
}

// ---------- 3-term S GEMM, 1-deep reg prefetch over single LDS buffer ----------
__global__ __launch_bounds__(512, 4) void sgemm3_k(
    const unsigned short* __restrict__ Qh, const unsigned short* __restrict__ Ql,
    const unsigned short* __restrict__ Kh, const unsigned short* __restrict__ Kl,
    float* __restrict__ S, int qbase)
{
  int bx = blockIdx.x, by = blockIdx.y;
  int q0g = qbase + bx*128, k0 = by*128;
  __shared__ unsigned short Qhs[128][72], Qls[128][72], Khs[128][72], Kls[128][72];
  int tid = threadIdx.x, w = tid >> 6, lane = tid & 63, lr = lane & 15, lg = lane >> 4;
  int wr = w & 1, wc = w >> 1;
  int row0 = tid >> 3, cgs = (tid & 7)*8;
  const unsigned short* gqh = Qh + (long)(q0g+row0)*512 + cgs;
  const unsigned short* gql = Ql + (long)(q0g+row0)*512 + cgs;
  const unsigned short* gkh = Kh + (long)(k0 +row0)*512 + cgs;
  const unsigned short* gkl = Kl + (long)(k0 +row0)*512 + cgs;
  const long R1 = (long)64*512;
  short8 r0,r1,r2,r3,r4,r5,r6,r7;
  f32x4 acc[4][2] = {};

#define SG_LOAD(CB) { long o_ = (long)(CB)*64; \
    r0 = *(const short8*)(gqh + o_);      r1 = *(const short8*)(gqh + R1 + o_); \
    r2 = *(const short8*)(gql + o_);      r3 = *(const short8*)(gql + R1 + o_); \
    r4 = *(const short8*)(gkh + o_);      r5 = *(const short8*)(gkh + R1 + o_); \
    r6 = *(const short8*)(gkl + o_);      r7 = *(const short8*)(gkl + R1 + o_); }
#define SG_WRITE { \
    *(short8*)&Qhs[row0][cgs] = r0; *(short8*)&Qhs[row0+64][cgs] = r1; \
    *(short8*)&Qls[row0][cgs] = r2; *(short8*)&Qls[row0+64][cgs] = r3; \
    *(short8*)&Khs[row0][cgs] = r4; *(short8*)&Khs[row0+64][cgs] = r5; \
    *(short8*)&Kls[row0][cgs] = r6; *(short8*)&Kls[row0+64][cgs] = r7; }

  SG_LOAD(0); SG_WRITE;
  __syncthreads();
  for (int cb = 0; cb < 8; ++cb){
    if (cb < 7) SG_LOAD(cb+1);
    #pragma unroll
    for (int kk = 0; kk < 2; ++kk){
      short8 bh[2], bl[2];
      #pragma unroll
      for (int bs = 0; bs < 2; ++bs){
        int krow = wc*32 + bs*16 + lr;
        bh[bs] = *(const short8*)(&Khs[krow][kk*32 + lg*8]);
        bl[bs] = *(const short8*)(&Kls[krow][kk*32 + lg*8]);
      }
      #pragma unroll
      for (int as = 0; as < 4; ++as){
        int qrow = wr*64 + as*16 + lr;
        short8 ah = *(const short8*)(&Qhs[qrow][kk*32 + lg*8]);
        short8 al = *(const short8*)(&Qls[qrow][kk*32 + lg*8]);
        #pragma unroll
        for (int bs = 0; bs < 2; ++bs){
          acc[as][bs] = MFMA(ah, bh[bs], acc[as][bs], 0,0,0);
          acc[as][bs] = MFMA(al, bh[bs], acc[as][bs], 0,0,0);
          acc[as][bs] = MFMA(ah, bl[bs], acc[as][bs], 0,0,0);
        }
      }
    }
    __syncthreads();
    if (cb < 7){ SG_WRITE; __syncthreads(); }
  }
#undef SG_LOAD
#undef SG_WRITE
  #pragma unroll
  for (int as = 0; as < 4; ++as){
    #pragma unroll
    for (int bs = 0; bs < 2; ++bs){
      int q = bx*128 + wr*64 + as*16 + lg*4;
      int k = k0 + wc*32 + bs*16 + lr;
      float* Sp = S + (long)q*4096 + k;
      #pragma unroll
      for (int r = 0; r < 4; ++r) Sp[(long)r*4096] = acc[as][bs][r];
    }
  }
}

// ---------- row softmax ----------
__global__ __launch_bounds__(256) void softmax_k(const float* __restrict__ S,
                                                 unsigned short* __restrict__ Pb, long pitch,
                                                 int row0, float* __restrict__ inv2){
  int row = blockIdx.x;
  const float* Sr = S + (long)row * 4096;
  int t = threadIdx.x;
  f32x4 v[4];
  #pragma unroll
  for (int i = 0; i < 4; ++i) v[i] = *(const f32x4*)(Sr + t*4 + i*1024);
  float mx = v[0][0];
  #pragma unroll
  for (int i = 0; i < 4; ++i)
    #pragma unroll
    for (int j = 0; j < 4; ++j) mx = fmaxf(mx, v[i][j]);
  #pragma unroll
  for (int o = 32; o > 0; o >>= 1) mx = fmaxf(mx, __shfl_xor(mx, o));
  __shared__ float red[4];
  int wid = t >> 6;
  if ((t & 63) == 0) red[wid] = mx;
  __syncthreads();
  mx = fmaxf(fmaxf(red[0], red[1]), fmaxf(red[2], red[3]));
  __syncthreads();
  float p[16]; float d = 0.f;
  #pragma unroll
  for (int i = 0; i < 4; ++i)
    #pragma unroll
    for (int j = 0; j < 4; ++j){ float e = expf(v[i][j] - mx); p[i*4+j] = e; d += e; }
  #pragma unroll
  for (int o = 32; o > 0; o >>= 1) d += __shfl_xor(d, o);
  if ((t & 63) == 0) red[wid] = d;
  __syncthreads();
  d = red[0] + red[1] + red[2] + red[3];
  __syncthreads();
  float invd = 1.f / d;
  unsigned short pb[16]; float d2 = 0.f;
  #pragma unroll
  for (int i = 0; i < 16; ++i){ pb[i] = f2bf(p[i] * invd); d2 += bf2f(pb[i]); }
  #pragma unroll
  for (int o = 32; o > 0; o >>= 1) d2 += __shfl_xor(d2, o);
  if ((t & 63) == 0) red[wid] = d2;
  __syncthreads();
  if (t == 0) inv2[row0 + row] = 1.f / (red[0]+red[1]+red[2]+red[3]);
  unsigned short* Pr = Pb + (long)(row0 + row) * pitch;
  #pragma unroll
  for (int i = 0; i < 4; ++i){
    u16x4 pk;
    #pragma unroll
    for (int j = 0; j < 4; ++j) pk[j] = pb[i*4+j];
    *(u16x4*)(Pr + t*4 + i*1024) = pk;
  }
}

// ---------- PV GEMM + epilogue, 2-deep reg prefetch, double-buffered LDS ----------
__global__ __launch_bounds__(512, 2) void pv2_k(
    const unsigned short* __restrict__ P, long ppitch,
    const unsigned short* __restrict__ vh, const unsigned short* __restrict__ vl,
    const unsigned short* __restrict__ v2h, const unsigned short* __restrict__ v2l,
    const float* __restrict__ inv2,
    const float* __restrict__ cx, const float* __restrict__ mcx, const float* __restrict__ rcx,
    float* __restrict__ outb, int qP_base, int qG_base)
{
  __shared__ __align__(16) char smem[110592];           // 108 KB
  typedef unsigned short (*PlT)[128][72];               // Pl[2][128][72]
  typedef unsigned short (*VlT)[4][64][72];             // Vl[2][4][64][72]
  PlT Pl = (PlT)smem;
  VlT Vl = (VlT)(smem + 36864);
  float* R = (float*)smem;

  int tid = threadIdx.x;
  int l = tid & 63, w = tid >> 6;
  int s = w & 1, wv = (w >> 1) & 1, wq = w >> 2;
  int lr = l & 15, lg = l >> 4;
  int qP0 = qP_base + blockIdx.x*128, qG0 = qG_base + blockIdx.x*128;
  int vc0 = blockIdx.y*64;

  int rowA = tid >> 3, c8 = (tid & 7)*8;
  const unsigned short* pgA = P + (long)(qP0 + rowA)*ppitch + c8;
  const unsigned short* pgB = pgA + (long)64*ppitch;
  long vgo = (long)(vc0 + rowA)*4096 + c8;
  const unsigned short* vg0 = vh  + vgo;
  const unsigned short* vg1 = vl  + vgo;
  const unsigned short* vg2 = v2h + vgo;
  const unsigned short* vg3 = v2l + vgo;

  f32x4 accM[4][2] = {}, acc2[4][2] = {};
  short8 pA0,pA1,vA0,vA1,vA2,vA3, pB0,pB1,vB0,vB1,vB2,vB3;
  int kc = s*32 + lg*8;

#define PV_LOAD(P0,P1,V0,V1,V2,V3, TT) { long ko_ = (long)(TT)*64; \
    P0 = *(const short8*)(pgA + ko_); P1 = *(const short8*)(pgB + ko_); \
    V0 = *(const short8*)(vg0 + ko_); V1 = *(const short8*)(vg1 + ko_); \
    V2 = *(const short8*)(vg2 + ko_); V3 = *(const short8*)(vg3 + ko_); }
#define PV_WRITE(BUF, P0,P1,V0,V1,V2,V3) { \
    *(short8*)&Pl[BUF][rowA][c8] = P0;    *(short8*)&Pl[BUF][rowA+64][c8] = P1; \
    *(short8*)&Vl[BUF][0][rowA][c8] = V0; *(short8*)&Vl[BUF][1][rowA][c8] = V1; \
    *(short8*)&Vl[BUF][2][rowA][c8] = V2; *(short8*)&Vl[BUF][3][rowA][c8] = V3; }
#define PV_COMPUTE(BUF) { \
    short8 fh[2], fl2[2], f2h[2], f2l[2]; \
    _Pragma("unroll") for (int bs = 0; bs < 2; ++bs){ \
      int vrow = wv*32 + bs*16 + lr; \
      fh[bs]  = *(const short8*)(&Vl[BUF][0][vrow][kc]); \
      fl2[bs] = *(const short8*)(&Vl[BUF][1][vrow][kc]); \
      f2h[bs] = *(const short8*)(&Vl[BUF][2][vrow][kc]); \
      f2l[bs] = *(const short8*)(&Vl[BUF][3][vrow][kc]); } \
    _Pragma("unroll") for (int aq = 0; aq < 4; ++aq){ \
      short8 pa = *(const short8*)(&Pl[BUF][wq*64 + aq*16 + lr][kc]); \
      _Pragma("unroll") for (int bs = 0; bs < 2; ++bs){ \
        accM[aq][bs] = MFMA(pa, fh[bs],  accM[aq][bs], 0,0,0); \
        accM[aq][bs] = MFMA(pa, fl2[bs], accM[aq][bs], 0,0,0); \
        acc2[aq][bs] = MFMA(pa, f2h[bs], acc2[aq][bs], 0,0,0); \
        acc2[aq][bs] = MFMA(pa, f2l[bs], acc2[aq][bs], 0,0,0); } } }

  // prologue: tile0 -> LDS0 ; tile1 -> regs A
  PV_LOAD(pA0,pA1,vA0,vA1,vA2,vA3, 0);
  PV_WRITE(0, pA0,pA1,vA0,vA1,vA2,vA3);
  PV_LOAD(pA0,pA1,vA0,vA1,vA2,vA3, 1);
  __syncthreads();

  for (int t = 0; t < 64; t += 2){
    // even: compute tile t (buf0); write tile t+1 (regs A) -> buf1; load tile t+2 -> B
    if (t+2 < 64) PV_LOAD(pB0,pB1,vB0,vB1,vB2,vB3, t+2);
    PV_COMPUTE(0);
    PV_WRITE(1, pA0,pA1,vA0,vA1,vA2,vA3);
    __syncthreads();
    // odd: compute tile t+1 (buf1); write tile t+2 (regs B) -> buf0; load tile t+3 -> A
    if (t+3 < 64) PV_LOAD(pA0,pA1,vA0,vA1,vA2,vA3, t+3);
    PV_COMPUTE(1);
    if (t+2 < 64) PV_WRITE(0, pB0,pB1,vB0,vB1,vB2,vB3);
    __syncthreads();
  }
#undef PV_LOAD
#undef PV_WRITE
#undef PV_COMPUTE

  // ---- k-substep reduce: s=1 waves dump, s=0 partners add ----
  if (s == 1){
    float* Rb = R + (w>>1)*4096 + l*64;
    #pragma unroll
    for (int aq = 0; aq < 4; ++aq)
      #pragma unroll
      for (int bs = 0; bs < 2; ++bs)
        #pragma unroll
        for (int r = 0; r < 4; ++r){
          Rb[(aq*2+bs)*4 + r]      = accM[aq][bs][r];
          Rb[32 + (aq*2+bs)*4 + r] = acc2[aq][bs][r];
        }
  }
  __syncthreads();
  if (s == 0){
    const float* Rb = R + (w>>1)*4096 + l*64;
    #pragma unroll
    for (int aq = 0; aq < 4; ++aq)
      #pragma unroll
      for (int bs = 0; bs < 2; ++bs)
        #pragma unroll
        for (int r = 0; r < 4; ++r){
          accM[aq][bs][r] += Rb[(aq*2+bs)*4 + r];
          acc2[aq][bs][r] += Rb[32 + (aq*2+bs)*4 + r];
        }
  }
  __syncthreads();
  // ---- transpose to LDS: Tm/T2 [vc 64][q 128+pad4] ----
  float* Tm = R;
  float* T2 = R + 64*132;
  if (s == 0){
    #pragma unroll
    for (int aq = 0; aq < 4; ++aq)
      #pragma unroll
      for (int bs = 0; bs < 2; ++bs){
        int vcl = wv*32 + bs*16 + lr;
        int ql = wq*64 + aq*16 + lg*4;
        #pragma unroll
        for (int r = 0; r < 4; ++r){
          Tm[vcl*132 + ql + r] = accM[aq][bs][r];
          T2[vcl*132 + ql + r] = acc2[aq][bs][r];
        }
      }
  }
  __syncthreads();
  // ---- blend + coalesced store ----
  #pragma unroll
  for (int p = 0; p < 4; ++p){
    int chunk = tid + p*512;
    int row = chunk >> 5, c4 = (chunk & 31)*4;
    float mu = mcx[vc0 + row], rs = rcx[vc0 + row];
    f32x4 tm = *(const f32x4*)&Tm[row*132 + c4];
    f32x4 t2 = *(const f32x4*)&T2[row*132 + c4];
    f32x4 iv = *(const f32x4*)&inv2[qP0 + c4];
    f32x4 cv = *(const f32x4*)&cx[(long)(vc0+row)*4096 + qG0 + c4];
    f32x4 ov;
    #pragma unroll
    for (int j = 0; j < 4; ++j){
      float M = tm[j]*iv[j], M2 = t2[j]*iv[j];
      float var = M2 - M*M;
      float sd = sqrtf(fmaxf(var, 0.f));
      ov[j] = sd*(cv[j]-mu)*rs + M;
    }
    *(f32x4*)&outb[(long)(vc0+row)*4096 + qG0 + c4] = ov;
  }
}

// ---------- launch ----------
extern "C" void kernel_launch(void* const* d_in, const int* in_sizes, int n_in,
                              void* d_out, int out_size, void* d_ws, size_t ws_size,
                              hipStream_t stream){
  const float* c_x  = (const float*)d_in[0];
  const float* s_x  = (const float*)d_in[1];
  const float* c_1x = (const float*)d_in[2];
  const float* s_1x = (const float*)d_in[3];
  const float* f_w  = (const float*)d_in[4];
  const float* f_b  = (const float*)d_in[5];
  const float* g_w  = (const float*)d_in[6];
  const float* g_b  = (const float*)d_in[7];
  const float* h_w  = (const float*)d_in[8];
  const float* h_b  = (const float*)d_in[9];
  float* out = (float*)d_out;

  char* ws = (char*)d_ws;
  size_t off = 0;
  auto alloc = [&](size_t bytes)->void*{
    void* p = ws + off; off += (bytes + 255) & ~(size_t)255; return p;
  };
  float* meanQ = (float*)alloc(2048*4); float* rstdQ = (float*)alloc(2048*4);
  float* meanK = (float*)alloc(2048*4); float* rstdK = (float*)alloc(2048*4);
  float* meanC = (float*)alloc(2048*4); float* rstdC = (float*)alloc(2048*4);
  float* biasF = (float*)alloc(512*4);  float* biasG = (float*)alloc(512*4);
  unsigned short* Wfh = (unsigned short*)alloc((size_t)512*512*2);
  unsigned short* Wfl = (unsigned short*)alloc((size_t)512*512*2);
  unsigned short* Wgh = (unsigned short*)alloc((size_t)512*512*2);
  unsigned short* Wgl = (unsigned short*)alloc((size_t)512*512*2);
  unsigned short* Whh = (unsigned short*)alloc((size_t)512*512*2);
  unsigned short* Whl = (unsigned short*)alloc((size_t)512*512*2);
  unsigned short* Qh = (unsigned short*)alloc((size_t)4096*512*2);
  unsigned short* Ql = (unsigned short*)alloc((size_t)4096*512*2);
  unsigned short* Kh = (unsigned short*)alloc((size_t)4096*512*2);
  unsigned short* Kl = (unsigned short*)alloc((size_t)4096*512*2);
  unsigned short* vh  = (unsigned short*)alloc((size_t)512*4096*2);
  unsigned short* vl  = (unsigned short*)alloc((size_t)512*4096*2);
  unsigned short* v2h = (unsigned short*)alloc((size_t)512*4096*2);
  unsigned short* v2l = (unsigned short*)alloc((size_t)512*4096*2);
  float* S    = (float*)alloc((size_t)2048*4096*4);   // fp32 S chunk
  float* inv2 = (float*)alloc(4096*4);

  size_t pbytes = (size_t)4096*4096*2;
  bool bigP = (off + pbytes + 256 <= ws_size);
  unsigned short* Pb; long ppitch;
  if (bigP){ Pb = (unsigned short*)alloc(pbytes); ppitch = 4096; }
  else     { Pb = (unsigned short*)S;             ppitch = 8192; }

  rowstats_k<<<2048, 256, 0, stream>>>(c_1x, meanQ, rstdQ);
  rowstats_k<<<2048, 256, 0, stream>>>(s_1x, meanK, rstdK);
  rowstats_k<<<2048, 256, 0, stream>>>(c_x,  meanC, rstdC);
  wsplit_k<<<1024, 256, 0, stream>>>(h_w, Whh, Whl);

  for (int b = 0; b < 4; ++b){
    long xoff = (long)b * 512 * 4096;
    foldw_k<<<512, 256, 0, stream>>>(f_w, f_b, meanQ + b*512, rstdQ + b*512, Wfh, Wfl, biasF);
    foldw_k<<<512, 256, 0, stream>>>(g_w, g_b, meanK + b*512, rstdK + b*512, Wgh, Wgl, biasG);
    conv3_k<0><<<dim3(64,4), 512, 0, stream>>>(c_1x + xoff, Wfh, Wfl, biasF, Qh, Ql, nullptr, nullptr);
    conv3_k<0><<<dim3(64,4), 512, 0, stream>>>(s_1x + xoff, Wgh, Wgl, biasG, Kh, Kl, nullptr, nullptr);
    conv3_k<1><<<dim3(64,4), 512, 0, stream>>>(s_x + xoff, Whh, Whl, h_b, vh, vl, v2h, v2l);
    if (bigP){
      for (int ch = 0; ch < 2; ++ch){
        int qbase = ch * 2048;
        sgemm3_k<<<dim3(16,32), 512, 0, stream>>>(Qh, Ql, Kh, Kl, S, qbase);
        softmax_k<<<2048, 256, 0, stream>>>(S, Pb, 4096, qbase, inv2);
      }
      pv2_k<<<dim3(32,8), 512, 0, stream>>>(Pb, 4096, vh, vl, v2h, v2l, inv2,
                                            c_x + xoff, meanC + b*512, rstdC + b*512,
                                            out + xoff, 0, 0);
    } else {
      for (int ch = 0; ch < 2; ++ch){
        int qbase = ch * 2048;
        sgemm3_k<<<dim3(16,32), 512, 0, stream>>>(Qh, Ql, Kh, Kl, S, qbase);
        softmax_k<<<2048, 256, 0, stream>>>(S, Pb, 8192, 0, inv2);
        pv2_k<<<dim3(16,8), 512, 0, stream>>>(Pb, 8192, vh, vl, v2h, v2l, inv2,
                                              c_x + xoff, meanC + b*512, rstdC + b*512,
                                              out + xoff, 0, qbase);
      }
    }
  }
}